// Round 1
// baseline (866.704 us; speedup 1.0000x reference)
//
#include <hip/hip_runtime.h>

#define N_NODES 100000
#define N_EDGES 1600000

#define BNODES 32
#define NBUCK 3125          // 100000 / 32 exactly
#define NSUB 8              // one sub-bucket per XCD (blockIdx & 7)
#define SUBCAP 128          // mean 64, ~8 sigma headroom

typedef unsigned int uint;
typedef unsigned short u16;
typedef __attribute__((ext_vector_type(8))) short bf16x8;  // 8 bf16 (4 VGPRs)
typedef __attribute__((ext_vector_type(4))) float f32x4;

__device__ __forceinline__ uint bf16_rtne(float f) {
  uint u = __float_as_uint(f);
  return (u + 0x7fffu + ((u >> 16) & 1u)) >> 16;
}

// ---------------- bucketed edge staging ----------------

__global__ __launch_bounds__(256) void k_zero_cur(int* __restrict__ bcur) {
  int i = blockIdx.x * 256 + threadIdx.x;
  if (i < NBUCK * NSUB) bcur[i] = 0;
}

// Append edges into dst-buckets; sub-bucket = blockIdx&7 keeps each stage
// region + cursor owned by ONE XCD's L2 (round-robin dispatch) -> ~1x write amp.
__global__ __launch_bounds__(256) void k_bucket(const int* __restrict__ ei, int* __restrict__ bcur,
                                                uint* __restrict__ stage) {
  int e = blockIdx.x * 256 + threadIdx.x;
  int sub = blockIdx.x & (NSUB - 1);
  if (e < N_EDGES) {
    int s = ei[e];
    int d = ei[N_EDGES + e];
    int b = d >> 5;
    int idx = sub * NBUCK + b;
    int pos = atomicAdd(&bcur[idx], 1);
    if (pos < SUBCAP)  // overflow guard (statistically unreachable)
      stage[idx * SUBCAP + pos] = (uint)s | ((uint)(d & 31) << 17);
  }
}

// per-bucket degree count (LDS only) -> dinv + bucket total (for the small scan)
__global__ __launch_bounds__(256) void k_bcount(const int* __restrict__ bcur, const uint* __restrict__ stage,
                                                float* __restrict__ dinv, int* __restrict__ btot) {
  __shared__ int cnt[BNODES];
  int b = blockIdx.x, t = threadIdx.x;
  if (t < BNODES) cnt[t] = 0;
  __syncthreads();
  int tot = 0;
  for (int s = 0; s < NSUB; ++s) {
    int idx = s * NBUCK + b;
    int n = bcur[idx]; if (n > SUBCAP) n = SUBCAP;
    tot += n;
    int base = idx * SUBCAP;
    for (int i = t; i < n; i += 256) atomicAdd(&cnt[stage[base + i] >> 17], 1);
  }
  __syncthreads();
  if (t < BNODES) dinv[b * BNODES + t] = rsqrtf((float)(cnt[t] + 1));  // +1 self-loop
  if (t == 0) btot[b] = tot;
}

// single-block exclusive scan over 3125 bucket totals -> bucketbase
__global__ __launch_bounds__(256) void k_bscan(const int* __restrict__ btot, int* __restrict__ bbase,
                                               int* __restrict__ rowptr) {
  __shared__ int sd[256];
  const int t = threadIdx.x;
  const int per = (NBUCK + 255) / 256;  // 13
  int v[13];
  int s = 0;
#pragma unroll
  for (int j = 0; j < per; ++j) {
    int i = t * per + j;
    v[j] = (i < NBUCK) ? btot[i] : 0;
    s += v[j];
  }
  sd[t] = s;
  __syncthreads();
  for (int off = 1; off < 256; off <<= 1) {
    int a = (t >= off) ? sd[t - off] : 0;
    __syncthreads();
    sd[t] += a;
    __syncthreads();
  }
  int run = sd[t] - s;  // exclusive prefix of this thread's chunk
#pragma unroll
  for (int j = 0; j < per; ++j) {
    int i = t * per + j;
    if (i < NBUCK) { bbase[i] = run; run += v[j]; }
  }
  if (t == 255) rowptr[N_NODES] = run;
}

// fused: recount -> 32-wide scan -> rowptr -> scatter (src,dinv[src]) into CSR range
__global__ __launch_bounds__(256) void k_scatter(const int* __restrict__ bcur, const uint* __restrict__ stage,
                                                 const int* __restrict__ bbase, const float* __restrict__ dinv,
                                                 int* __restrict__ rowptr, int2* __restrict__ ep) {
  __shared__ int cnt[BNODES];
  __shared__ int cur[BNODES];
  int b = blockIdx.x, t = threadIdx.x;
  if (t < BNODES) cnt[t] = 0;
  __syncthreads();
  for (int s = 0; s < NSUB; ++s) {
    int idx = s * NBUCK + b;
    int n = bcur[idx]; if (n > SUBCAP) n = SUBCAP;
    int base = idx * SUBCAP;
    for (int i = t; i < n; i += 256) atomicAdd(&cnt[stage[base + i] >> 17], 1);
  }
  __syncthreads();
  if (t < BNODES) {
    int pre = 0;
#pragma unroll
    for (int j = 0; j < BNODES; ++j) pre += (j < t) ? cnt[j] : 0;
    int c = bbase[b] + pre;
    cur[t] = c;
    rowptr[b * BNODES + t] = c;
  }
  __syncthreads();
  for (int s = 0; s < NSUB; ++s) {
    int idx = s * NBUCK + b;
    int n = bcur[idx]; if (n > SUBCAP) n = SUBCAP;
    int base = idx * SUBCAP;
    for (int i = t; i < n; i += 256) {
      uint u = stage[base + i];
      int src = (int)(u & 0x1FFFFu);
      int dl = (int)(u >> 17);
      int pos = atomicAdd(&cur[dl], 1);
      int2 pr;
      pr.x = src;
      pr.y = __float_as_int(dinv[src]);
      ep[pos] = pr;
    }
  }
}

// ---------------- W pre-swizzle to MFMA B-fragment order ----------------

__global__ __launch_bounds__(256) void k_prepw(const float* __restrict__ W1, const float* __restrict__ W2,
                                               uint* __restrict__ S1, uint* __restrict__ S2) {
  int u = blockIdx.x * 256 + threadIdx.x;  // 0..2047
  const float* W = blockIdx.y ? W2 : W1;
  uint* S = blockIdx.y ? S2 : S1;
  int lane = u & 63;
  int kcnt = u >> 6;
  int kc = kcnt & 3;
  int nt = kcnt >> 2;
  int n = nt * 16 + (lane & 15);
  int k0 = kc * 32 + (lane >> 4) * 8;
  float f[8];
#pragma unroll
  for (int j = 0; j < 8; ++j) f[j] = W[(size_t)(k0 + j) * 128 + n];
  uint4 pk;
  pk.x = bf16_rtne(f[0]) | (bf16_rtne(f[1]) << 16);
  pk.y = bf16_rtne(f[2]) | (bf16_rtne(f[3]) << 16);
  pk.z = bf16_rtne(f[4]) | (bf16_rtne(f[5]) << 16);
  pk.w = bf16_rtne(f[6]) | (bf16_rtne(f[7]) << 16);
  ((uint4*)S)[u] = pk;
}

// ---------------- MFMA GEMM: OutH[nrows,128](bf16) = A[nrows,128] @ W ----------------
// 64 rows/block, 4 waves, wave w owns rows w*16..w*16+15, sweeps 8 n-tiles.
// Output is written in XCD-SLICED layout: slice s = channel>>4 (== nt),
// element (node,channel c) -> OutH[((s*N_NODES)+node)*16 + (c&15)].
// Slice = 3.2 MB -> fits one XCD's 4 MB L2 for the aggregation gather.

__global__ __launch_bounds__(256) void k_gemm(const void* __restrict__ Ain, int a_f32,
                                              const uint* __restrict__ Wsw,
                                              u16* __restrict__ OutH, int nrows) {
  __shared__ uint As[4096];   // 16 KB A fragments
  __shared__ uint Bs[8192];   // 32 KB B fragments
  const int tid = threadIdx.x;
  const int R = blockIdx.x * 64;
  {
    const uint4* src = (const uint4*)Wsw;
    uint4* dst = (uint4*)Bs;
#pragma unroll
    for (int v = 0; v < 8; ++v) dst[tid + v * 256] = src[tid + v * 256];
  }
  const int unit = tid & 15;      // k8-slice 0..15
  const int kc_s = unit >> 2;
  const int quad_s = unit & 3;
#pragma unroll
  for (int pass = 0; pass < 4; ++pass) {
    int row = pass * 16 + (tid >> 4);
    int gr = R + row;
    if (gr >= nrows) gr = nrows - 1;
    uint4 pk;
    if (a_f32) {
      const float* srcr = (const float*)Ain + (size_t)gr * 128 + unit * 8;
      float4 f0 = ((const float4*)srcr)[0];
      float4 f1 = ((const float4*)srcr)[1];
      pk.x = bf16_rtne(f0.x) | (bf16_rtne(f0.y) << 16);
      pk.y = bf16_rtne(f0.z) | (bf16_rtne(f0.w) << 16);
      pk.z = bf16_rtne(f1.x) | (bf16_rtne(f1.y) << 16);
      pk.w = bf16_rtne(f1.z) | (bf16_rtne(f1.w) << 16);
    } else {
      pk = ((const uint4*)((const uint*)Ain + (size_t)gr * 64))[unit];
    }
    int lane_t = quad_s * 16 + (row & 15);
    *(uint4*)&As[((pass * 4 + kc_s) * 64 + lane_t) * 4] = pk;
  }
  __syncthreads();

  const int w = tid >> 6;
  const int lane = tid & 63;
  bf16x8 a0 = *(bf16x8*)&As[((w * 4 + 0) * 64 + lane) * 4];
  bf16x8 a1 = *(bf16x8*)&As[((w * 4 + 1) * 64 + lane) * 4];
  bf16x8 a2 = *(bf16x8*)&As[((w * 4 + 2) * 64 + lane) * 4];
  bf16x8 a3 = *(bf16x8*)&As[((w * 4 + 3) * 64 + lane) * 4];
  f32x4 acc[8];
#pragma unroll
  for (int nt = 0; nt < 8; ++nt) acc[nt] = (f32x4){0.f, 0.f, 0.f, 0.f};
#pragma unroll
  for (int nt = 0; nt < 8; ++nt) {
    bf16x8 b0 = *(bf16x8*)&Bs[((nt * 4 + 0) * 64 + lane) * 4];
    bf16x8 b1 = *(bf16x8*)&Bs[((nt * 4 + 1) * 64 + lane) * 4];
    bf16x8 b2 = *(bf16x8*)&Bs[((nt * 4 + 2) * 64 + lane) * 4];
    bf16x8 b3 = *(bf16x8*)&Bs[((nt * 4 + 3) * 64 + lane) * 4];
    acc[nt] = __builtin_amdgcn_mfma_f32_16x16x32_bf16(a0, b0, acc[nt], 0, 0, 0);
    acc[nt] = __builtin_amdgcn_mfma_f32_16x16x32_bf16(a1, b1, acc[nt], 0, 0, 0);
    acc[nt] = __builtin_amdgcn_mfma_f32_16x16x32_bf16(a2, b2, acc[nt], 0, 0, 0);
    acc[nt] = __builtin_amdgcn_mfma_f32_16x16x32_bf16(a3, b3, acc[nt], 0, 0, 0);
  }
  const int colb = lane & 15;
  const int quad = lane >> 4;
#pragma unroll
  for (int nt = 0; nt < 8; ++nt) {
#pragma unroll
    for (int r = 0; r < 4; ++r) {
      int gr = R + w * 16 + quad * 4 + r;
      if (gr < nrows)
        OutH[((size_t)nt * N_NODES + gr) * 16 + colb] = (u16)bf16_rtne(acc[nt][r]);
    }
  }
}

// ---------------- Aggregation: XCD channel-sliced gather ----------------
// slice = blockIdx&7 -> lands on one XCD (round-robin dispatch); its 3.2 MB
// hb-slice stays L2-resident. Wave = 8 edge-groups x 8 uints; each iteration
// gathers 8 edges x 32B. ep/output use nontemporal ops to avoid evicting
// the gather table. 3-step shfl_xor reduce combines the 8 edge-groups.

__device__ __forceinline__ void bacc(float& ax, float& ay, uint v, float w) {
  ax += w * __uint_as_float(v << 16);
  ay += w * __uint_as_float(v & 0xffff0000u);
}

__global__ __launch_bounds__(256) void k_agg(const uint* __restrict__ hb, const float* __restrict__ dinv,
                                             const int* __restrict__ rowptr, const int2* __restrict__ ep,
                                             const float* __restrict__ bias,
                                             u16* __restrict__ outb, float* __restrict__ outf) {
  const int wid = threadIdx.x >> 6;
  const int lane = threadIdx.x & 63;
  const int slice = blockIdx.x & 7;
  const int chunk = blockIdx.x >> 3;
  const int g = lane >> 3;   // edge group 0..7
  const int u = lane & 7;    // uint within 32B slice row
  const uint* tab = hb + (size_t)slice * N_NODES * 8;
  const int nb = chunk * 16 + wid * 4;   // 16 nodes per block, 4 per wave

#pragma unroll 1
  for (int j = 0; j < 4; ++j) {
    const int node = nb + j;
    const int beg = rowptr[node];
    const int end = rowptr[node + 1];
    const float dn = dinv[node];
    float ax = 0.f, ay = 0.f;
    if (g == 7) {  // self-loop handled by one group
      uint v = tab[(size_t)node * 8 + u];
      bacc(ax, ay, v, dn);
    }
    int e = beg;
    for (; e + 16 <= end; e += 16) {
      long long q0 = __builtin_nontemporal_load((const long long*)&ep[e + g]);
      long long q1 = __builtin_nontemporal_load((const long long*)&ep[e + 8 + g]);
      int s0 = (int)q0;
      int s1 = (int)q1;
      uint v0 = tab[(size_t)s0 * 8 + u];
      uint v1 = tab[(size_t)s1 * 8 + u];
      bacc(ax, ay, v0, __uint_as_float((uint)(q0 >> 32)));
      bacc(ax, ay, v1, __uint_as_float((uint)(q1 >> 32)));
    }
    for (; e + 8 <= end; e += 8) {
      long long q0 = __builtin_nontemporal_load((const long long*)&ep[e + g]);
      int s0 = (int)q0;
      uint v0 = tab[(size_t)s0 * 8 + u];
      bacc(ax, ay, v0, __uint_as_float((uint)(q0 >> 32)));
    }
    int rem = end - e;
    if (g < rem) {
      long long q0 = __builtin_nontemporal_load((const long long*)&ep[e + g]);
      int s0 = (int)q0;
      uint v0 = tab[(size_t)s0 * 8 + u];
      bacc(ax, ay, v0, __uint_as_float((uint)(q0 >> 32)));
    }
    // reduce over the 8 edge-groups (lanes u, u+8, ..., u+56)
    ax += __shfl_xor(ax, 8);  ay += __shfl_xor(ay, 8);
    ax += __shfl_xor(ax, 16); ay += __shfl_xor(ay, 16);
    ax += __shfl_xor(ax, 32); ay += __shfl_xor(ay, 32);
    if (g == 0) {
      const int c = slice * 16 + u * 2;
      float rx = dn * ax + bias[c];
      float ry = dn * ay + bias[c + 1];
      if (outb) {
        uint pk = bf16_rtne(rx) | (bf16_rtne(ry) << 16);
        __builtin_nontemporal_store(pk, (uint*)(outb + (size_t)node * 128 + c));
      } else {
        long long ov = ((long long)(unsigned long long)__float_as_uint(ry) << 32) |
                       (unsigned long long)__float_as_uint(rx);
        __builtin_nontemporal_store(ov, (long long*)(outf + (size_t)node * 128 + c));
      }
    }
  }
}

// ---------------- launch ----------------

extern "C" void kernel_launch(void* const* d_in, const int* in_sizes, int n_in,
                              void* d_out, int out_size, void* d_ws, size_t ws_size,
                              hipStream_t stream) {
  const float* x  = (const float*)d_in[0];
  const int*   ei = (const int*)d_in[1];   // int32: [0..E)=src, [E..2E)=dst
  const float* W1 = (const float*)d_in[2];
  const float* b1 = (const float*)d_in[3];
  const float* W2 = (const float*)d_in[4];
  const float* b2 = (const float*)d_in[5];
  float* out = (float*)d_out;

  char* p = (char*)d_ws;
  uint*  hb     = (uint*)p;  p += (size_t)N_NODES * 64 * sizeof(uint);            // 25.6 MB bf16 h table (sliced)
  int2*  ep     = (int2*)p;  p += (size_t)N_EDGES * sizeof(int2);                 // 12.8 MB
  uint*  stage  = (uint*)p;  p += (size_t)NBUCK * NSUB * SUBCAP * sizeof(uint);   // 12.8 MB
  uint*  wsw1   = (uint*)p;  p += 8192 * sizeof(uint);                            // 32 KB
  uint*  wsw2   = (uint*)p;  p += 8192 * sizeof(uint);                            // 32 KB
  int*   bcur   = (int*)p;   p += (size_t)NBUCK * NSUB * sizeof(int);             // 100 KB
  float* dinv   = (float*)p; p += (size_t)N_NODES * sizeof(float);                // 400 KB
  int*   rowptr = (int*)p;   p += (size_t)(N_NODES + 1) * sizeof(int);            // 400 KB
  int*   btot   = (int*)p;   p += (size_t)NBUCK * sizeof(int);
  int*   bbase  = (int*)p;

  // h1 (bf16 layer-1 activation) lives in d_out scratch: written by agg1,
  // consumed by gemm2, then agg2 overwrites all of d_out.
  u16* h1b = (u16*)d_out;

  const int GG = (N_NODES + 63) / 64;   // 1563
  const int GA = (N_NODES / 16) * 8;    // 6250 chunks x 8 slices = 50000

  k_zero_cur<<<(NBUCK * NSUB + 255) / 256, 256, 0, stream>>>(bcur);
  k_bucket<<<(N_EDGES + 255) / 256, 256, 0, stream>>>(ei, bcur, stage);
  k_bcount<<<NBUCK, 256, 0, stream>>>(bcur, stage, dinv, btot);
  k_bscan<<<1, 256, 0, stream>>>(btot, bbase, rowptr);
  k_scatter<<<NBUCK, 256, 0, stream>>>(bcur, stage, bbase, dinv, rowptr, ep);
  k_prepw<<<dim3(8, 2), 256, 0, stream>>>(W1, W2, wsw1, wsw2);

  // layer 1
  k_gemm<<<GG, 256, 0, stream>>>(x, 1, wsw1, (u16*)hb, N_NODES);
  k_agg<<<GA, 256, 0, stream>>>(hb, dinv, rowptr, ep, b1, h1b, nullptr);
  // layer 2
  k_gemm<<<GG, 256, 0, stream>>>(h1b, 0, wsw2, (u16*)hb, N_NODES);
  k_agg<<<GA, 256, 0, stream>>>(hb, dinv, rowptr, ep, b2, nullptr, out);
}

// Round 2
// 370.188 us; speedup vs baseline: 2.3412x; 2.3412x over previous
//
#include <hip/hip_runtime.h>

#define N_NODES 100000
#define N_EDGES 1600000

#define BNODES 32
#define NBUCK 3125          // 100000 / 32 exactly
#define NSUB 8              // one sub-bucket per XCD (blockIdx & 7)
#define SUBCAP 128          // mean 64, ~8 sigma headroom

typedef unsigned int uint;
typedef unsigned short u16;
typedef __attribute__((ext_vector_type(8))) short bf16x8;  // 8 bf16 (4 VGPRs)
typedef __attribute__((ext_vector_type(4))) float f32x4;

__device__ __forceinline__ uint bf16_rtne(float f) {
  uint u = __float_as_uint(f);
  return (u + 0x7fffu + ((u >> 16) & 1u)) >> 16;
}

// ---------------- bucketed edge staging ----------------

__global__ __launch_bounds__(256) void k_zero_cur(int* __restrict__ bcur) {
  int i = blockIdx.x * 256 + threadIdx.x;
  if (i < NBUCK * NSUB) bcur[i] = 0;
}

// Append edges into dst-buckets; sub-bucket = blockIdx&7 keeps each stage
// region + cursor owned by ONE XCD's L2 (round-robin dispatch) -> ~1x write amp.
__global__ __launch_bounds__(256) void k_bucket(const int* __restrict__ ei, int* __restrict__ bcur,
                                                uint* __restrict__ stage) {
  int e = blockIdx.x * 256 + threadIdx.x;
  int sub = blockIdx.x & (NSUB - 1);
  if (e < N_EDGES) {
    int s = ei[e];
    int d = ei[N_EDGES + e];
    int b = d >> 5;
    int idx = sub * NBUCK + b;
    int pos = atomicAdd(&bcur[idx], 1);
    if (pos < SUBCAP)  // overflow guard (statistically unreachable)
      stage[idx * SUBCAP + pos] = (uint)s | ((uint)(d & 31) << 17);
  }
}

// per-bucket degree count (LDS only) -> dinv + bucket total + persisted counts
__global__ __launch_bounds__(256) void k_bcount(const int* __restrict__ bcur, const uint* __restrict__ stage,
                                                float* __restrict__ dinv, int* __restrict__ btot,
                                                int* __restrict__ bcnt) {
  __shared__ int cnt[BNODES];
  int b = blockIdx.x, t = threadIdx.x;
  if (t < BNODES) cnt[t] = 0;
  __syncthreads();
  int tot = 0;
  for (int s = 0; s < NSUB; ++s) {
    int idx = s * NBUCK + b;
    int n = bcur[idx]; if (n > SUBCAP) n = SUBCAP;
    tot += n;
    int base = idx * SUBCAP;
    for (int i = t; i < n; i += 256) atomicAdd(&cnt[stage[base + i] >> 17], 1);
  }
  __syncthreads();
  if (t < BNODES) {
    dinv[b * BNODES + t] = rsqrtf((float)(cnt[t] + 1));  // +1 self-loop
    bcnt[b * BNODES + t] = cnt[t];                       // persist for k_scatter
  }
  if (t == 0) btot[b] = tot;
}

// single-block exclusive scan over 3125 bucket totals -> bucketbase
__global__ __launch_bounds__(256) void k_bscan(const int* __restrict__ btot, int* __restrict__ bbase,
                                               int* __restrict__ rowptr) {
  __shared__ int sd[256];
  const int t = threadIdx.x;
  const int per = (NBUCK + 255) / 256;  // 13
  int v[13];
  int s = 0;
#pragma unroll
  for (int j = 0; j < per; ++j) {
    int i = t * per + j;
    v[j] = (i < NBUCK) ? btot[i] : 0;
    s += v[j];
  }
  sd[t] = s;
  __syncthreads();
  for (int off = 1; off < 256; off <<= 1) {
    int a = (t >= off) ? sd[t - off] : 0;
    __syncthreads();
    sd[t] += a;
    __syncthreads();
  }
  int run = sd[t] - s;  // exclusive prefix of this thread's chunk
#pragma unroll
  for (int j = 0; j < per; ++j) {
    int i = t * per + j;
    if (i < NBUCK) { bbase[i] = run; run += v[j]; }
  }
  if (t == 255) rowptr[N_NODES] = run;
}

// fused: load persisted counts -> 32-wide scan -> rowptr -> scatter (src,dinv[src])
__global__ __launch_bounds__(256) void k_scatter(const int* __restrict__ bcur, const uint* __restrict__ stage,
                                                 const int* __restrict__ bbase, const float* __restrict__ dinv,
                                                 const int* __restrict__ bcnt,
                                                 int* __restrict__ rowptr, int2* __restrict__ ep) {
  __shared__ int cur[BNODES];
  int b = blockIdx.x, t = threadIdx.x;
  if (t < BNODES) {
    // prefix over this bucket's 32 persisted counts
    int pre = 0;
#pragma unroll
    for (int j = 0; j < BNODES; ++j) pre += (j < t) ? bcnt[b * BNODES + j] : 0;
    int c = bbase[b] + pre;
    cur[t] = c;
    rowptr[b * BNODES + t] = c;
  }
  __syncthreads();
  for (int s = 0; s < NSUB; ++s) {
    int idx = s * NBUCK + b;
    int n = bcur[idx]; if (n > SUBCAP) n = SUBCAP;
    int base = idx * SUBCAP;
    for (int i = t; i < n; i += 256) {
      uint u = stage[base + i];
      int src = (int)(u & 0x1FFFFu);
      int dl = (int)(u >> 17);
      int pos = atomicAdd(&cur[dl], 1);
      int2 pr;
      pr.x = src;
      pr.y = __float_as_int(dinv[src]);
      ep[pos] = pr;
    }
  }
}

// ---------------- W pre-swizzle to MFMA B-fragment order ----------------

__global__ __launch_bounds__(256) void k_prepw(const float* __restrict__ W1, const float* __restrict__ W2,
                                               uint* __restrict__ S1, uint* __restrict__ S2) {
  int u = blockIdx.x * 256 + threadIdx.x;  // 0..2047
  const float* W = blockIdx.y ? W2 : W1;
  uint* S = blockIdx.y ? S2 : S1;
  int lane = u & 63;
  int kcnt = u >> 6;
  int kc = kcnt & 3;
  int nt = kcnt >> 2;
  int n = nt * 16 + (lane & 15);
  int k0 = kc * 32 + (lane >> 4) * 8;
  float f[8];
#pragma unroll
  for (int j = 0; j < 8; ++j) f[j] = W[(size_t)(k0 + j) * 128 + n];
  uint4 pk;
  pk.x = bf16_rtne(f[0]) | (bf16_rtne(f[1]) << 16);
  pk.y = bf16_rtne(f[2]) | (bf16_rtne(f[3]) << 16);
  pk.z = bf16_rtne(f[4]) | (bf16_rtne(f[5]) << 16);
  pk.w = bf16_rtne(f[6]) | (bf16_rtne(f[7]) << 16);
  ((uint4*)S)[u] = pk;
}

// ---------------- MFMA GEMM: OutH[nrows,128](bf16) = A[nrows,128] @ W ----------------
// 64 rows/block, 4 waves, wave w owns rows w*16..w*16+15, sweeps 8 n-tiles.

__global__ __launch_bounds__(256) void k_gemm(const void* __restrict__ Ain, int a_f32,
                                              const uint* __restrict__ Wsw,
                                              u16* __restrict__ OutH, int nrows) {
  __shared__ uint As[4096];   // 16 KB A fragments
  __shared__ uint Bs[8192];   // 32 KB B fragments
  const int tid = threadIdx.x;
  const int R = blockIdx.x * 64;
  {
    const uint4* src = (const uint4*)Wsw;
    uint4* dst = (uint4*)Bs;
#pragma unroll
    for (int v = 0; v < 8; ++v) dst[tid + v * 256] = src[tid + v * 256];
  }
  const int unit = tid & 15;      // k8-slice 0..15
  const int kc_s = unit >> 2;
  const int quad_s = unit & 3;
#pragma unroll
  for (int pass = 0; pass < 4; ++pass) {
    int row = pass * 16 + (tid >> 4);
    int gr = R + row;
    if (gr >= nrows) gr = nrows - 1;
    uint4 pk;
    if (a_f32) {
      const float* srcr = (const float*)Ain + (size_t)gr * 128 + unit * 8;
      float4 f0 = ((const float4*)srcr)[0];
      float4 f1 = ((const float4*)srcr)[1];
      pk.x = bf16_rtne(f0.x) | (bf16_rtne(f0.y) << 16);
      pk.y = bf16_rtne(f0.z) | (bf16_rtne(f0.w) << 16);
      pk.z = bf16_rtne(f1.x) | (bf16_rtne(f1.y) << 16);
      pk.w = bf16_rtne(f1.z) | (bf16_rtne(f1.w) << 16);
    } else {
      pk = ((const uint4*)((const uint*)Ain + (size_t)gr * 64))[unit];
    }
    int lane_t = quad_s * 16 + (row & 15);
    *(uint4*)&As[((pass * 4 + kc_s) * 64 + lane_t) * 4] = pk;
  }
  __syncthreads();

  const int w = tid >> 6;
  const int lane = tid & 63;
  bf16x8 a0 = *(bf16x8*)&As[((w * 4 + 0) * 64 + lane) * 4];
  bf16x8 a1 = *(bf16x8*)&As[((w * 4 + 1) * 64 + lane) * 4];
  bf16x8 a2 = *(bf16x8*)&As[((w * 4 + 2) * 64 + lane) * 4];
  bf16x8 a3 = *(bf16x8*)&As[((w * 4 + 3) * 64 + lane) * 4];
  f32x4 acc[8];
#pragma unroll
  for (int nt = 0; nt < 8; ++nt) acc[nt] = (f32x4){0.f, 0.f, 0.f, 0.f};
#pragma unroll
  for (int nt = 0; nt < 8; ++nt) {
    bf16x8 b0 = *(bf16x8*)&Bs[((nt * 4 + 0) * 64 + lane) * 4];
    bf16x8 b1 = *(bf16x8*)&Bs[((nt * 4 + 1) * 64 + lane) * 4];
    bf16x8 b2 = *(bf16x8*)&Bs[((nt * 4 + 2) * 64 + lane) * 4];
    bf16x8 b3 = *(bf16x8*)&Bs[((nt * 4 + 3) * 64 + lane) * 4];
    acc[nt] = __builtin_amdgcn_mfma_f32_16x16x32_bf16(a0, b0, acc[nt], 0, 0, 0);
    acc[nt] = __builtin_amdgcn_mfma_f32_16x16x32_bf16(a1, b1, acc[nt], 0, 0, 0);
    acc[nt] = __builtin_amdgcn_mfma_f32_16x16x32_bf16(a2, b2, acc[nt], 0, 0, 0);
    acc[nt] = __builtin_amdgcn_mfma_f32_16x16x32_bf16(a3, b3, acc[nt], 0, 0, 0);
  }
  const int colb = lane & 15;
  const int quad = lane >> 4;
#pragma unroll
  for (int nt = 0; nt < 8; ++nt) {
#pragma unroll
    for (int r = 0; r < 4; ++r) {
      int gr = R + w * 16 + quad * 4 + r;
      if (gr < nrows)
        OutH[(size_t)gr * 128 + nt * 16 + colb] = (u16)bf16_rtne(acc[nt][r]);
    }
  }
}

// ---------------- Aggregation: one wave per node, deep-ILP register accum ----------------
// 8 independent 256B row-gathers in flight per wave (R0 had 4); ep reads are
// wave-uniform (broadcast). Mean degree 16 -> main loop ~2 iterations.

__device__ __forceinline__ void bacc(float& ax, float& ay, uint v, float w) {
  ax += w * __uint_as_float(v << 16);
  ay += w * __uint_as_float(v & 0xffff0000u);
}

__global__ __launch_bounds__(256) void k_agg(const uint* __restrict__ hb, const float* __restrict__ dinv,
                                             const int* __restrict__ rowptr, const int2* __restrict__ ep,
                                             const float* __restrict__ bias,
                                             u16* __restrict__ outb, float* __restrict__ outf) {
  int wid = threadIdx.x >> 6;
  int lane = threadIdx.x & 63;
  int node = blockIdx.x * 4 + wid;
  if (node >= N_NODES) return;
  int beg = rowptr[node];
  int end = rowptr[node + 1];
  float dn = dinv[node];
  uint selfv = hb[(size_t)node * 64 + lane];
  float ax = 0.f, ay = 0.f;
  bacc(ax, ay, selfv, dn);

  int e = beg;
  for (; e + 8 <= end; e += 8) {
    int2 p[8];
#pragma unroll
    for (int j = 0; j < 8; ++j) p[j] = ep[e + j];
    uint v[8];
#pragma unroll
    for (int j = 0; j < 8; ++j) v[j] = hb[(size_t)p[j].x * 64 + lane];
#pragma unroll
    for (int j = 0; j < 8; ++j) bacc(ax, ay, v[j], __int_as_float(p[j].y));
  }
  if (e + 4 <= end) {
    int2 p[4];
#pragma unroll
    for (int j = 0; j < 4; ++j) p[j] = ep[e + j];
    uint v[4];
#pragma unroll
    for (int j = 0; j < 4; ++j) v[j] = hb[(size_t)p[j].x * 64 + lane];
#pragma unroll
    for (int j = 0; j < 4; ++j) bacc(ax, ay, v[j], __int_as_float(p[j].y));
    e += 4;
  }
  for (; e < end; ++e) {
    int2 p = ep[e];
    uint v = hb[(size_t)p.x * 64 + lane];
    bacc(ax, ay, v, __int_as_float(p.y));
  }

  int c = lane * 2;
  float rx = dn * ax + bias[c];
  float ry = dn * ay + bias[c + 1];
  if (outb) {
    uint pk = bf16_rtne(rx) | (bf16_rtne(ry) << 16);
    *(uint*)(outb + (size_t)node * 128 + c) = pk;
  } else {
    float2 o; o.x = rx; o.y = ry;
    *(float2*)(outf + (size_t)node * 128 + c) = o;
  }
}

// ---------------- launch ----------------

extern "C" void kernel_launch(void* const* d_in, const int* in_sizes, int n_in,
                              void* d_out, int out_size, void* d_ws, size_t ws_size,
                              hipStream_t stream) {
  const float* x  = (const float*)d_in[0];
  const int*   ei = (const int*)d_in[1];   // int32: [0..E)=src, [E..2E)=dst
  const float* W1 = (const float*)d_in[2];
  const float* b1 = (const float*)d_in[3];
  const float* W2 = (const float*)d_in[4];
  const float* b2 = (const float*)d_in[5];
  float* out = (float*)d_out;

  char* p = (char*)d_ws;
  uint*  hb     = (uint*)p;  p += (size_t)N_NODES * 64 * sizeof(uint);            // 25.6 MB bf16 h table
  int2*  ep     = (int2*)p;  p += (size_t)N_EDGES * sizeof(int2);                 // 12.8 MB
  uint*  stage  = (uint*)p;  p += (size_t)NBUCK * NSUB * SUBCAP * sizeof(uint);   // 12.8 MB
  uint*  wsw1   = (uint*)p;  p += 8192 * sizeof(uint);                            // 32 KB
  uint*  wsw2   = (uint*)p;  p += 8192 * sizeof(uint);                            // 32 KB
  int*   bcur   = (int*)p;   p += (size_t)NBUCK * NSUB * sizeof(int);             // 100 KB
  float* dinv   = (float*)p; p += (size_t)N_NODES * sizeof(float);                // 400 KB
  int*   rowptr = (int*)p;   p += (size_t)(N_NODES + 1) * sizeof(int);            // 400 KB
  int*   bcnt   = (int*)p;   p += (size_t)NBUCK * BNODES * sizeof(int);           // 400 KB
  int*   btot   = (int*)p;   p += (size_t)NBUCK * sizeof(int);
  int*   bbase  = (int*)p;

  // h1 (bf16 layer-1 activation) lives in d_out scratch: written by agg1,
  // consumed by gemm2, then agg2 overwrites all of d_out.
  u16* h1b = (u16*)d_out;

  const int GG = (N_NODES + 63) / 64;  // 1563

  k_zero_cur<<<(NBUCK * NSUB + 255) / 256, 256, 0, stream>>>(bcur);
  k_bucket<<<(N_EDGES + 255) / 256, 256, 0, stream>>>(ei, bcur, stage);
  k_bcount<<<NBUCK, 256, 0, stream>>>(bcur, stage, dinv, btot, bcnt);
  k_bscan<<<1, 256, 0, stream>>>(btot, bbase, rowptr);
  k_scatter<<<NBUCK, 256, 0, stream>>>(bcur, stage, bbase, dinv, bcnt, rowptr, ep);
  k_prepw<<<dim3(8, 2), 256, 0, stream>>>(W1, W2, wsw1, wsw2);

  // layer 1
  k_gemm<<<GG, 256, 0, stream>>>(x, 1, wsw1, (u16*)hb, N_NODES);
  k_agg<<<(N_NODES + 3) / 4, 256, 0, stream>>>(hb, dinv, rowptr, ep, b1, h1b, nullptr);
  // layer 2
  k_gemm<<<GG, 256, 0, stream>>>(h1b, 0, wsw2, (u16*)hb, N_NODES);
  k_agg<<<(N_NODES + 3) / 4, 256, 0, stream>>>(hb, dinv, rowptr, ep, b2, nullptr, out);
}

// Round 3
// 334.642 us; speedup vs baseline: 2.5899x; 1.1062x over previous
//
#include <hip/hip_runtime.h>

#define N_NODES 100000
#define N_EDGES 1600000

#define NBIN 196            // ceil(100000 / 512) dst-bins
#define BINCAP 9216         // mean 8163, sigma ~90 -> 11+ sigma headroom
#define NPB 4096            // edges per partition block
#define PBLK ((N_EDGES + NPB - 1) / NPB)   // 391

typedef unsigned int uint;
typedef unsigned short u16;
typedef __attribute__((ext_vector_type(8))) short bf16x8;  // 8 bf16 (4 VGPRs)
typedef __attribute__((ext_vector_type(4))) float f32x4;

__device__ __forceinline__ uint bf16_rtne(float f) {
  uint u = __float_as_uint(f);
  return (u + 0x7fffu + ((u >> 16) & 1u)) >> 16;
}

// ---------------- coarse-bin counting-sort partition ----------------

__global__ __launch_bounds__(256) void k_zerobc(int* __restrict__ bin_cur) {
  if (threadIdx.x < NBIN) bin_cur[threadIdx.x] = 0;
}

// Partition edges into 196 dst-bins (512 nodes each). Per-block LDS histogram,
// ONE global atomic per (block,bin) range reservation (77K atomics total vs
// 1.6M in the old k_bucket), then dense scatter into the reserved chunk.
// Payload: src(17b) | dst_low9(9b)<<17  -> 26 bits in u32.
__global__ __launch_bounds__(256) void k_part(const int* __restrict__ ei, int* __restrict__ bin_cur,
                                              uint* __restrict__ stage) {
  __shared__ uint hist[NBIN];
  __shared__ uint lcur[NBIN];
  __shared__ uint base[NBIN];
  const int t = threadIdx.x;
  const int e0 = blockIdx.x * NPB;
  for (int i = t; i < NBIN; i += 256) { hist[i] = 0; lcur[i] = 0; }
  __syncthreads();
  // phase A: histogram of dst bins (dst stream only; lines stay L2-hot for B)
#pragma unroll
  for (int j = 0; j < NPB / 256; ++j) {
    int e = e0 + j * 256 + t;
    if (e < N_EDGES) atomicAdd(&hist[((uint)ei[N_EDGES + e]) >> 9], 1u);
  }
  __syncthreads();
  for (int i = t; i < NBIN; i += 256)
    base[i] = hist[i] ? atomicAdd((uint*)&bin_cur[i], hist[i]) : 0u;
  __syncthreads();
  // phase B: scatter into this block's dense reserved ranges
#pragma unroll
  for (int j = 0; j < NPB / 256; ++j) {
    int e = e0 + j * 256 + t;
    if (e < N_EDGES) {
      uint s = (uint)ei[e];
      uint d = (uint)ei[N_EDGES + e];
      uint b = d >> 9;
      uint l = atomicAdd(&lcur[b], 1u);
      uint pos = base[b] + l;
      if (pos < BINCAP)  // statistically unreachable guard
        stage[(size_t)b * BINCAP + pos] = s | ((d & 511u) << 17);
    }
  }
}

// scan 196 bin totals -> per-bin edge base (ebase) + rowptr[N_NODES]
__global__ __launch_bounds__(256) void k_binscan(const int* __restrict__ bin_cur,
                                                 int* __restrict__ ebase, int* __restrict__ rowptr) {
  __shared__ int sd[256];
  const int t = threadIdx.x;
  int v = (t < NBIN) ? min(bin_cur[t], BINCAP) : 0;
  int s = v;
  sd[t] = s;
  __syncthreads();
  for (int off = 1; off < 256; off <<= 1) {
    int a = (t >= off) ? sd[t - off] : 0;
    __syncthreads();
    sd[t] += a;
    __syncthreads();
  }
  if (t < NBIN) ebase[t] = sd[t] - v;
  if (t == 255) rowptr[N_NODES] = sd[255];
}

// per-bin degree count (512 local nodes, LDS) -> dinv + rowptr (LDS scan)
__global__ __launch_bounds__(256) void k_bin2a(const int* __restrict__ bin_cur, const uint* __restrict__ stage,
                                               const int* __restrict__ ebase,
                                               float* __restrict__ dinv, int* __restrict__ rowptr) {
  __shared__ int cnt[512];
  __shared__ int sd[256];
  const int b = blockIdx.x, t = threadIdx.x;
  cnt[t] = 0; cnt[t + 256] = 0;
  __syncthreads();
  const int n = min(bin_cur[b], BINCAP);
  const uint* sb = stage + (size_t)b * BINCAP;
  for (int i = t; i < n; i += 256) atomicAdd(&cnt[sb[i] >> 17], 1);
  __syncthreads();
  int v0 = cnt[t * 2], v1 = cnt[t * 2 + 1];
  int s = v0 + v1;
  sd[t] = s;
  __syncthreads();
  for (int off = 1; off < 256; off <<= 1) {
    int a = (t >= off) ? sd[t - off] : 0;
    __syncthreads();
    sd[t] += a;
    __syncthreads();
  }
  int run = sd[t] - s;  // exclusive prefix of this thread's 2 nodes
  int g0 = b * 512 + t * 2;
  int eb = ebase[b];
  if (g0 < N_NODES) {
    rowptr[g0] = eb + run;
    dinv[g0] = rsqrtf((float)(v0 + 1));  // +1 self-loop
  }
  if (g0 + 1 < N_NODES) {
    rowptr[g0 + 1] = eb + run + v0;
    dinv[g0 + 1] = rsqrtf((float)(v1 + 1));
  }
}

// per-bin scatter: (src, dinv[src]) into the bin's CONTIGUOUS ep region
__global__ __launch_bounds__(256) void k_bin2b(const int* __restrict__ bin_cur, const uint* __restrict__ stage,
                                               const int* __restrict__ rowptr, const float* __restrict__ dinv,
                                               int2* __restrict__ ep) {
  __shared__ int cur[512];
  const int b = blockIdx.x, t = threadIdx.x;
  const int g0 = b * 512;
  for (int l = t; l < 512; l += 256) {
    int g = g0 + l;
    cur[l] = (g < N_NODES) ? rowptr[g] : 0;
  }
  __syncthreads();
  const int n = min(bin_cur[b], BINCAP);
  const uint* sb = stage + (size_t)b * BINCAP;
  for (int i = t; i < n; i += 256) {
    uint u = sb[i];
    int s = (int)(u & 0x1FFFFu);
    int l = (int)(u >> 17);
    float w = dinv[s];
    int pos = atomicAdd(&cur[l], 1);
    int2 pr;
    pr.x = s;
    pr.y = __float_as_int(w);
    ep[pos] = pr;
  }
}

// ---------------- W pre-swizzle to MFMA B-fragment order ----------------

__global__ __launch_bounds__(256) void k_prepw(const float* __restrict__ W1, const float* __restrict__ W2,
                                               uint* __restrict__ S1, uint* __restrict__ S2) {
  int u = blockIdx.x * 256 + threadIdx.x;  // 0..2047
  const float* W = blockIdx.y ? W2 : W1;
  uint* S = blockIdx.y ? S2 : S1;
  int lane = u & 63;
  int kcnt = u >> 6;
  int kc = kcnt & 3;
  int nt = kcnt >> 2;
  int n = nt * 16 + (lane & 15);
  int k0 = kc * 32 + (lane >> 4) * 8;
  float f[8];
#pragma unroll
  for (int j = 0; j < 8; ++j) f[j] = W[(size_t)(k0 + j) * 128 + n];
  uint4 pk;
  pk.x = bf16_rtne(f[0]) | (bf16_rtne(f[1]) << 16);
  pk.y = bf16_rtne(f[2]) | (bf16_rtne(f[3]) << 16);
  pk.z = bf16_rtne(f[4]) | (bf16_rtne(f[5]) << 16);
  pk.w = bf16_rtne(f[6]) | (bf16_rtne(f[7]) << 16);
  ((uint4*)S)[u] = pk;
}

// ---------------- MFMA GEMM: OutH[nrows,128](bf16) = A[nrows,128] @ W ----------------
// 64 rows/block, 4 waves, wave w owns rows w*16..w*16+15, sweeps 8 n-tiles.

__global__ __launch_bounds__(256) void k_gemm(const void* __restrict__ Ain, int a_f32,
                                              const uint* __restrict__ Wsw,
                                              u16* __restrict__ OutH, int nrows) {
  __shared__ uint As[4096];   // 16 KB A fragments
  __shared__ uint Bs[8192];   // 32 KB B fragments
  const int tid = threadIdx.x;
  const int R = blockIdx.x * 64;
  {
    const uint4* src = (const uint4*)Wsw;
    uint4* dst = (uint4*)Bs;
#pragma unroll
    for (int v = 0; v < 8; ++v) dst[tid + v * 256] = src[tid + v * 256];
  }
  const int unit = tid & 15;      // k8-slice 0..15
  const int kc_s = unit >> 2;
  const int quad_s = unit & 3;
#pragma unroll
  for (int pass = 0; pass < 4; ++pass) {
    int row = pass * 16 + (tid >> 4);
    int gr = R + row;
    if (gr >= nrows) gr = nrows - 1;
    uint4 pk;
    if (a_f32) {
      const float* srcr = (const float*)Ain + (size_t)gr * 128 + unit * 8;
      float4 f0 = ((const float4*)srcr)[0];
      float4 f1 = ((const float4*)srcr)[1];
      pk.x = bf16_rtne(f0.x) | (bf16_rtne(f0.y) << 16);
      pk.y = bf16_rtne(f0.z) | (bf16_rtne(f0.w) << 16);
      pk.z = bf16_rtne(f1.x) | (bf16_rtne(f1.y) << 16);
      pk.w = bf16_rtne(f1.z) | (bf16_rtne(f1.w) << 16);
    } else {
      pk = ((const uint4*)((const uint*)Ain + (size_t)gr * 64))[unit];
    }
    int lane_t = quad_s * 16 + (row & 15);
    *(uint4*)&As[((pass * 4 + kc_s) * 64 + lane_t) * 4] = pk;
  }
  __syncthreads();

  const int w = tid >> 6;
  const int lane = tid & 63;
  bf16x8 a0 = *(bf16x8*)&As[((w * 4 + 0) * 64 + lane) * 4];
  bf16x8 a1 = *(bf16x8*)&As[((w * 4 + 1) * 64 + lane) * 4];
  bf16x8 a2 = *(bf16x8*)&As[((w * 4 + 2) * 64 + lane) * 4];
  bf16x8 a3 = *(bf16x8*)&As[((w * 4 + 3) * 64 + lane) * 4];
  f32x4 acc[8];
#pragma unroll
  for (int nt = 0; nt < 8; ++nt) acc[nt] = (f32x4){0.f, 0.f, 0.f, 0.f};
#pragma unroll
  for (int nt = 0; nt < 8; ++nt) {
    bf16x8 b0 = *(bf16x8*)&Bs[((nt * 4 + 0) * 64 + lane) * 4];
    bf16x8 b1 = *(bf16x8*)&Bs[((nt * 4 + 1) * 64 + lane) * 4];
    bf16x8 b2 = *(bf16x8*)&Bs[((nt * 4 + 2) * 64 + lane) * 4];
    bf16x8 b3 = *(bf16x8*)&Bs[((nt * 4 + 3) * 64 + lane) * 4];
    acc[nt] = __builtin_amdgcn_mfma_f32_16x16x32_bf16(a0, b0, acc[nt], 0, 0, 0);
    acc[nt] = __builtin_amdgcn_mfma_f32_16x16x32_bf16(a1, b1, acc[nt], 0, 0, 0);
    acc[nt] = __builtin_amdgcn_mfma_f32_16x16x32_bf16(a2, b2, acc[nt], 0, 0, 0);
    acc[nt] = __builtin_amdgcn_mfma_f32_16x16x32_bf16(a3, b3, acc[nt], 0, 0, 0);
  }
  const int colb = lane & 15;
  const int quad = lane >> 4;
#pragma unroll
  for (int nt = 0; nt < 8; ++nt) {
#pragma unroll
    for (int r = 0; r < 4; ++r) {
      int gr = R + w * 16 + quad * 4 + r;
      if (gr < nrows)
        OutH[(size_t)gr * 128 + nt * 16 + colb] = (u16)bf16_rtne(acc[nt][r]);
    }
  }
}

// ---------------- Aggregation: one wave per node, deep-ILP register accum ----------------

__device__ __forceinline__ void bacc(float& ax, float& ay, uint v, float w) {
  ax += w * __uint_as_float(v << 16);
  ay += w * __uint_as_float(v & 0xffff0000u);
}

__global__ __launch_bounds__(256) void k_agg(const uint* __restrict__ hb, const float* __restrict__ dinv,
                                             const int* __restrict__ rowptr, const int2* __restrict__ ep,
                                             const float* __restrict__ bias,
                                             u16* __restrict__ outb, float* __restrict__ outf) {
  int wid = threadIdx.x >> 6;
  int lane = threadIdx.x & 63;
  int node = blockIdx.x * 4 + wid;
  if (node >= N_NODES) return;
  int beg = rowptr[node];
  int end = rowptr[node + 1];
  float dn = dinv[node];
  uint selfv = hb[(size_t)node * 64 + lane];
  float ax = 0.f, ay = 0.f;
  bacc(ax, ay, selfv, dn);

  int e = beg;
  for (; e + 8 <= end; e += 8) {
    int2 p[8];
#pragma unroll
    for (int j = 0; j < 8; ++j) p[j] = ep[e + j];
    uint v[8];
#pragma unroll
    for (int j = 0; j < 8; ++j) v[j] = hb[(size_t)p[j].x * 64 + lane];
#pragma unroll
    for (int j = 0; j < 8; ++j) bacc(ax, ay, v[j], __int_as_float(p[j].y));
  }
  if (e + 4 <= end) {
    int2 p[4];
#pragma unroll
    for (int j = 0; j < 4; ++j) p[j] = ep[e + j];
    uint v[4];
#pragma unroll
    for (int j = 0; j < 4; ++j) v[j] = hb[(size_t)p[j].x * 64 + lane];
#pragma unroll
    for (int j = 0; j < 4; ++j) bacc(ax, ay, v[j], __int_as_float(p[j].y));
    e += 4;
  }
  for (; e < end; ++e) {
    int2 p = ep[e];
    uint v = hb[(size_t)p.x * 64 + lane];
    bacc(ax, ay, v, __int_as_float(p.y));
  }

  int c = lane * 2;
  float rx = dn * ax + bias[c];
  float ry = dn * ay + bias[c + 1];
  if (outb) {
    uint pk = bf16_rtne(rx) | (bf16_rtne(ry) << 16);
    *(uint*)(outb + (size_t)node * 128 + c) = pk;
  } else {
    float2 o; o.x = rx; o.y = ry;
    *(float2*)(outf + (size_t)node * 128 + c) = o;
  }
}

// ---------------- launch ----------------

extern "C" void kernel_launch(void* const* d_in, const int* in_sizes, int n_in,
                              void* d_out, int out_size, void* d_ws, size_t ws_size,
                              hipStream_t stream) {
  const float* x  = (const float*)d_in[0];
  const int*   ei = (const int*)d_in[1];   // int32: [0..E)=src, [E..2E)=dst
  const float* W1 = (const float*)d_in[2];
  const float* b1 = (const float*)d_in[3];
  const float* W2 = (const float*)d_in[4];
  const float* b2 = (const float*)d_in[5];
  float* out = (float*)d_out;

  char* p = (char*)d_ws;
  uint*  hb     = (uint*)p;  p += (size_t)N_NODES * 64 * sizeof(uint);            // 25.6 MB bf16 h table
  int2*  ep     = (int2*)p;  p += (size_t)N_EDGES * sizeof(int2);                 // 12.8 MB
  uint*  stage  = (uint*)p;  p += (size_t)NBIN * BINCAP * sizeof(uint);           // 7.2 MB
  uint*  wsw1   = (uint*)p;  p += 8192 * sizeof(uint);                            // 32 KB
  uint*  wsw2   = (uint*)p;  p += 8192 * sizeof(uint);                            // 32 KB
  float* dinv   = (float*)p; p += (size_t)N_NODES * sizeof(float);                // 400 KB
  int*   rowptr = (int*)p;   p += (size_t)(N_NODES + 1) * sizeof(int);            // 400 KB
  int*   bin_cur= (int*)p;   p += (size_t)NBIN * sizeof(int);
  int*   ebase  = (int*)p;   p += (size_t)NBIN * sizeof(int);

  // h1 (bf16 layer-1 activation) lives in d_out scratch: written by agg1,
  // consumed by gemm2, then agg2 overwrites all of d_out.
  u16* h1b = (u16*)d_out;

  const int GG = (N_NODES + 63) / 64;  // 1563

  k_zerobc<<<1, 256, 0, stream>>>(bin_cur);
  k_part<<<PBLK, 256, 0, stream>>>(ei, bin_cur, stage);
  k_binscan<<<1, 256, 0, stream>>>(bin_cur, ebase, rowptr);
  k_bin2a<<<NBIN, 256, 0, stream>>>(bin_cur, stage, ebase, dinv, rowptr);
  k_bin2b<<<NBIN, 256, 0, stream>>>(bin_cur, stage, rowptr, dinv, ep);
  k_prepw<<<dim3(8, 2), 256, 0, stream>>>(W1, W2, wsw1, wsw2);

  // layer 1
  k_gemm<<<GG, 256, 0, stream>>>(x, 1, wsw1, (u16*)hb, N_NODES);
  k_agg<<<(N_NODES + 3) / 4, 256, 0, stream>>>(hb, dinv, rowptr, ep, b1, h1b, nullptr);
  // layer 2
  k_gemm<<<GG, 256, 0, stream>>>(h1b, 0, wsw2, (u16*)hb, N_NODES);
  k_agg<<<(N_NODES + 3) / 4, 256, 0, stream>>>(hb, dinv, rowptr, ep, b2, nullptr, out);
}

// Round 4
// 319.008 us; speedup vs baseline: 2.7169x; 1.0490x over previous
//
#include <hip/hip_runtime.h>

#define N_NODES 100000
#define N_EDGES 1600000

#define NBIN 196            // ceil(100000 / 512) dst-bins
#define BINCAP 9216         // mean 8163, sigma ~90 -> 11+ sigma headroom
#define NPB 4096            // edges per partition block
#define EPT 16              // NPB / 256
#define BPT 36              // BINCAP / 256
#define PBLK ((N_EDGES + NPB - 1) / NPB)   // 391

typedef unsigned int uint;
typedef unsigned short u16;
typedef __attribute__((ext_vector_type(8))) short bf16x8;  // 8 bf16 (4 VGPRs)
typedef __attribute__((ext_vector_type(4))) float f32x4;

__device__ __forceinline__ uint bf16_rtne(float f) {
  uint u = __float_as_uint(f);
  return (u + 0x7fffu + ((u >> 16) & 1u)) >> 16;
}

// ---------------- coarse-bin counting-sort partition ----------------

__global__ __launch_bounds__(256) void k_zerobc(int* __restrict__ bin_cur) {
  if (threadIdx.x < NBIN) bin_cur[threadIdx.x] = 0;
}

// Partition edges into 196 dst-bins (512 nodes each).
// v2: dst kept in regs across phases (ei read once per stream);
// wave-replicated LDS hist/cursor (4 copies) -> ~4x lower LDS-atomic conflict.
__global__ __launch_bounds__(256) void k_part(const int* __restrict__ ei, int* __restrict__ bin_cur,
                                              uint* __restrict__ stage) {
  __shared__ uint hist[4][NBIN];
  __shared__ uint wbase[4][NBIN];
  __shared__ uint lcur[4][NBIN];
  const int t = threadIdx.x;
  const int w = t >> 6;
  const int e0 = blockIdx.x * NPB;
  for (int i = t; i < 4 * NBIN; i += 256) { (&hist[0][0])[i] = 0; (&lcur[0][0])[i] = 0; }
  __syncthreads();
  uint d[EPT];
#pragma unroll
  for (int j = 0; j < EPT; ++j) {
    int e = e0 + j * 256 + t;
    d[j] = (e < N_EDGES) ? (uint)ei[N_EDGES + e] : 0xFFFFFFFFu;
    if (d[j] != 0xFFFFFFFFu) atomicAdd(&hist[w][d[j] >> 9], 1u);
  }
  __syncthreads();
  if (t < NBIN) {
    uint h0 = hist[0][t], h1 = hist[1][t], h2 = hist[2][t], h3 = hist[3][t];
    uint tot = h0 + h1 + h2 + h3;
    uint g = tot ? (uint)atomicAdd(&bin_cur[t], (int)tot) : 0u;
    wbase[0][t] = g;
    wbase[1][t] = g + h0;
    wbase[2][t] = g + h0 + h1;
    wbase[3][t] = g + h0 + h1 + h2;
  }
  __syncthreads();
#pragma unroll
  for (int j = 0; j < EPT; ++j) {
    if (d[j] != 0xFFFFFFFFu) {
      int e = e0 + j * 256 + t;
      uint s = (uint)ei[e];
      uint b = d[j] >> 9;
      uint pos = wbase[w][b] + atomicAdd(&lcur[w][b], 1u);
      if (pos < BINCAP)  // statistically unreachable guard
        stage[(size_t)b * BINCAP + pos] = s | ((d[j] & 511u) << 17);
    }
  }
}

// scan 196 bin totals -> per-bin edge base (ebase) + rowptr[N_NODES]
__global__ __launch_bounds__(256) void k_binscan(const int* __restrict__ bin_cur,
                                                 int* __restrict__ ebase, int* __restrict__ rowptr) {
  __shared__ int sd[256];
  const int t = threadIdx.x;
  int v = (t < NBIN) ? min(bin_cur[t], BINCAP) : 0;
  int s = v;
  sd[t] = s;
  __syncthreads();
  for (int off = 1; off < 256; off <<= 1) {
    int a = (t >= off) ? sd[t - off] : 0;
    __syncthreads();
    sd[t] += a;
    __syncthreads();
  }
  if (t < NBIN) ebase[t] = sd[t] - v;
  if (t == 255) rowptr[N_NODES] = sd[255];
}

// fused bin pass: stage chunk -> regs (once), LDS degree count -> scan ->
// rowptr + dinv, then scatter src into the bin's CONTIGUOUS ep region.
// ep carries src only (4B); dinv[src] is looked up by the agg kernels.
__global__ __launch_bounds__(256) void k_bin2(const int* __restrict__ bin_cur, const uint* __restrict__ stage,
                                              const int* __restrict__ ebase,
                                              float* __restrict__ dinv, int* __restrict__ rowptr,
                                              int* __restrict__ ep) {
  __shared__ int cnt[512];
  __shared__ int sd[256];
  __shared__ int curs[512];
  const int b = blockIdx.x, t = threadIdx.x;
  cnt[t] = 0; cnt[t + 256] = 0;
  __syncthreads();
  const int n = min(bin_cur[b], BINCAP);
  const uint* sb = stage + (size_t)b * BINCAP;
  uint r[BPT];
#pragma unroll
  for (int j = 0; j < BPT; ++j) {
    int i = j * 256 + t;
    r[j] = (i < n) ? sb[i] : 0xFFFFFFFFu;
  }
#pragma unroll
  for (int j = 0; j < BPT; ++j)
    if (r[j] != 0xFFFFFFFFu) atomicAdd(&cnt[r[j] >> 17], 1);
  __syncthreads();
  int v0 = cnt[t * 2], v1 = cnt[t * 2 + 1];
  int s = v0 + v1;
  sd[t] = s;
  __syncthreads();
  for (int off = 1; off < 256; off <<= 1) {
    int a = (t >= off) ? sd[t - off] : 0;
    __syncthreads();
    sd[t] += a;
    __syncthreads();
  }
  int run = sd[t] - s;  // exclusive prefix of this thread's 2 nodes
  int eb = ebase[b];
  int c0 = eb + run, c1 = eb + run + v0;
  int g0 = b * 512 + t * 2;
  if (g0 < N_NODES) {
    rowptr[g0] = c0;
    dinv[g0] = rsqrtf((float)(v0 + 1));  // +1 self-loop
  }
  if (g0 + 1 < N_NODES) {
    rowptr[g0 + 1] = c1;
    dinv[g0 + 1] = rsqrtf((float)(v1 + 1));
  }
  curs[t * 2] = c0; curs[t * 2 + 1] = c1;
  __syncthreads();
#pragma unroll
  for (int j = 0; j < BPT; ++j)
    if (r[j] != 0xFFFFFFFFu) {
      int pos = atomicAdd(&curs[r[j] >> 17], 1);
      ep[pos] = (int)(r[j] & 0x1FFFFu);
    }
}

// ---------------- W pre-swizzle to MFMA B-fragment order ----------------

__global__ __launch_bounds__(256) void k_prepw(const float* __restrict__ W1, const float* __restrict__ W2,
                                               uint* __restrict__ S1, uint* __restrict__ S2) {
  int u = blockIdx.x * 256 + threadIdx.x;  // 0..2047
  const float* W = blockIdx.y ? W2 : W1;
  uint* S = blockIdx.y ? S2 : S1;
  int lane = u & 63;
  int kcnt = u >> 6;
  int kc = kcnt & 3;
  int nt = kcnt >> 2;
  int n = nt * 16 + (lane & 15);
  int k0 = kc * 32 + (lane >> 4) * 8;
  float f[8];
#pragma unroll
  for (int j = 0; j < 8; ++j) f[j] = W[(size_t)(k0 + j) * 128 + n];
  uint4 pk;
  pk.x = bf16_rtne(f[0]) | (bf16_rtne(f[1]) << 16);
  pk.y = bf16_rtne(f[2]) | (bf16_rtne(f[3]) << 16);
  pk.z = bf16_rtne(f[4]) | (bf16_rtne(f[5]) << 16);
  pk.w = bf16_rtne(f[6]) | (bf16_rtne(f[7]) << 16);
  ((uint4*)S)[u] = pk;
}

// ---------------- MFMA GEMM (layer 1): hb[nrows,128](bf16) = x[nrows,128] @ W1 ----------------

__global__ __launch_bounds__(256) void k_gemm(const void* __restrict__ Ain, int a_f32,
                                              const uint* __restrict__ Wsw,
                                              u16* __restrict__ OutH, int nrows) {
  __shared__ uint As[4096];   // 16 KB A fragments
  __shared__ uint Bs[8192];   // 32 KB B fragments
  const int tid = threadIdx.x;
  const int R = blockIdx.x * 64;
  {
    const uint4* src = (const uint4*)Wsw;
    uint4* dst = (uint4*)Bs;
#pragma unroll
    for (int v = 0; v < 8; ++v) dst[tid + v * 256] = src[tid + v * 256];
  }
  const int unit = tid & 15;      // k8-slice 0..15
  const int kc_s = unit >> 2;
  const int quad_s = unit & 3;
#pragma unroll
  for (int pass = 0; pass < 4; ++pass) {
    int row = pass * 16 + (tid >> 4);
    int gr = R + row;
    if (gr >= nrows) gr = nrows - 1;
    uint4 pk;
    if (a_f32) {
      const float* srcr = (const float*)Ain + (size_t)gr * 128 + unit * 8;
      float4 f0 = ((const float4*)srcr)[0];
      float4 f1 = ((const float4*)srcr)[1];
      pk.x = bf16_rtne(f0.x) | (bf16_rtne(f0.y) << 16);
      pk.y = bf16_rtne(f0.z) | (bf16_rtne(f0.w) << 16);
      pk.z = bf16_rtne(f1.x) | (bf16_rtne(f1.y) << 16);
      pk.w = bf16_rtne(f1.z) | (bf16_rtne(f1.w) << 16);
    } else {
      pk = ((const uint4*)((const uint*)Ain + (size_t)gr * 64))[unit];
    }
    int lane_t = quad_s * 16 + (row & 15);
    *(uint4*)&As[((pass * 4 + kc_s) * 64 + lane_t) * 4] = pk;
  }
  __syncthreads();

  const int w = tid >> 6;
  const int lane = tid & 63;
  bf16x8 a0 = *(bf16x8*)&As[((w * 4 + 0) * 64 + lane) * 4];
  bf16x8 a1 = *(bf16x8*)&As[((w * 4 + 1) * 64 + lane) * 4];
  bf16x8 a2 = *(bf16x8*)&As[((w * 4 + 2) * 64 + lane) * 4];
  bf16x8 a3 = *(bf16x8*)&As[((w * 4 + 3) * 64 + lane) * 4];
  f32x4 acc[8];
#pragma unroll
  for (int nt = 0; nt < 8; ++nt) acc[nt] = (f32x4){0.f, 0.f, 0.f, 0.f};
#pragma unroll
  for (int nt = 0; nt < 8; ++nt) {
    bf16x8 b0 = *(bf16x8*)&Bs[((nt * 4 + 0) * 64 + lane) * 4];
    bf16x8 b1 = *(bf16x8*)&Bs[((nt * 4 + 1) * 64 + lane) * 4];
    bf16x8 b2 = *(bf16x8*)&Bs[((nt * 4 + 2) * 64 + lane) * 4];
    bf16x8 b3 = *(bf16x8*)&Bs[((nt * 4 + 3) * 64 + lane) * 4];
    acc[nt] = __builtin_amdgcn_mfma_f32_16x16x32_bf16(a0, b0, acc[nt], 0, 0, 0);
    acc[nt] = __builtin_amdgcn_mfma_f32_16x16x32_bf16(a1, b1, acc[nt], 0, 0, 0);
    acc[nt] = __builtin_amdgcn_mfma_f32_16x16x32_bf16(a2, b2, acc[nt], 0, 0, 0);
    acc[nt] = __builtin_amdgcn_mfma_f32_16x16x32_bf16(a3, b3, acc[nt], 0, 0, 0);
  }
  const int colb = lane & 15;
  const int quad = lane >> 4;
#pragma unroll
  for (int nt = 0; nt < 8; ++nt) {
#pragma unroll
    for (int r = 0; r < 4; ++r) {
      int gr = R + w * 16 + quad * 4 + r;
      if (gr < nrows)
        OutH[(size_t)gr * 128 + nt * 16 + colb] = (u16)bf16_rtne(acc[nt][r]);
    }
  }
}

// ---------------- helpers ----------------

__device__ __forceinline__ void bacc(float& ax, float& ay, uint v, float w) {
  ax += w * __uint_as_float(v << 16);
  ay += w * __uint_as_float(v & 0xffff0000u);
}

// aggregate one node into (ax, ay); lane holds channels {2*lane, 2*lane+1}
__device__ __forceinline__ void agg_node(const uint* __restrict__ hb, const float* __restrict__ dinv,
                                         const int* __restrict__ ep, int node, int lane,
                                         int beg, int end, float dn, float& ax, float& ay) {
  uint selfv = hb[(size_t)node * 64 + lane];
  bacc(ax, ay, selfv, dn);
  int e = beg;
  for (; e + 8 <= end; e += 8) {
    int p[8];
#pragma unroll
    for (int j = 0; j < 8; ++j) p[j] = ep[e + j];
    float wt[8];
#pragma unroll
    for (int j = 0; j < 8; ++j) wt[j] = dinv[p[j]];
    uint v[8];
#pragma unroll
    for (int j = 0; j < 8; ++j) v[j] = hb[(size_t)p[j] * 64 + lane];
#pragma unroll
    for (int j = 0; j < 8; ++j) bacc(ax, ay, v[j], wt[j]);
  }
  if (e + 4 <= end) {
    int p[4];
#pragma unroll
    for (int j = 0; j < 4; ++j) p[j] = ep[e + j];
    float wt[4];
#pragma unroll
    for (int j = 0; j < 4; ++j) wt[j] = dinv[p[j]];
    uint v[4];
#pragma unroll
    for (int j = 0; j < 4; ++j) v[j] = hb[(size_t)p[j] * 64 + lane];
#pragma unroll
    for (int j = 0; j < 4; ++j) bacc(ax, ay, v[j], wt[j]);
    e += 4;
  }
  for (; e < end; ++e) {
    int p = ep[e];
    float wt = dinv[p];
    uint v = hb[(size_t)p * 64 + lane];
    bacc(ax, ay, v, wt);
  }
}

// ---------------- fused agg(layer1) + GEMM(layer2) ----------------
// Block = 16 nodes (4 per wave, sequential). Aggregated rows -> 4 KB
// XOR-swizzled LDS A-tile -> in-block 16x128 @ 128x128 MFMA GEMM with
// B-fragments loaded straight from the L2-hot pre-swizzled W2 (no LDS B).
// Removes the 25.6 MB h1 write + 25.6 MB read + one dispatch.

__global__ __launch_bounds__(256) void k_aggm(const uint* __restrict__ hb, const float* __restrict__ dinv,
                                              const int* __restrict__ rowptr, const int* __restrict__ ep,
                                              const float* __restrict__ bias, const uint* __restrict__ Wsw,
                                              u16* __restrict__ outH) {
  __shared__ uint Abf[16 * 64];   // 4 KB swizzled bf16 A-tile
  const int w = threadIdx.x >> 6;
  const int lane = threadIdx.x & 63;
  const int nb = blockIdx.x * 16;
#pragma unroll 1
  for (int j = 0; j < 4; ++j) {
    const int lr = w * 4 + j;
    const int node = nb + lr;
    const int beg = rowptr[node];
    const int end = rowptr[node + 1];
    const float dn = dinv[node];
    float ax = 0.f, ay = 0.f;
    agg_node(hb, dinv, ep, node, lane, beg, end, dn, ax, ay);
    int c = lane * 2;
    float rx = dn * ax + bias[c];
    float ry = dn * ay + bias[c + 1];
    uint pk = bf16_rtne(rx) | (bf16_rtne(ry) << 16);
    Abf[(lr * 64 + lane) ^ ((lr & 7) << 2)] = pk;   // swizzled store
  }
  __syncthreads();
  // GEMM: C[16x128] = A[16x128] @ W2 ; wave w handles n-tiles {2w, 2w+1}
  const int row = lane & 15;
  const int kq = lane >> 4;
  bf16x8 a[4];
#pragma unroll
  for (int kc = 0; kc < 4; ++kc) {
    int ui = row * 64 + kc * 16 + kq * 4;
    a[kc] = *(bf16x8*)&Abf[ui ^ ((row & 7) << 2)];
  }
  const int colb = lane & 15;
  const int quad = lane >> 4;
#pragma unroll
  for (int nt2 = 0; nt2 < 2; ++nt2) {
    const int nt = w * 2 + nt2;
    f32x4 acc = (f32x4){0.f, 0.f, 0.f, 0.f};
#pragma unroll
    for (int kc = 0; kc < 4; ++kc) {
      bf16x8 bfr = *(const bf16x8*)((const uint4*)Wsw + (nt * 4 + kc) * 64 + lane);
      acc = __builtin_amdgcn_mfma_f32_16x16x32_bf16(a[kc], bfr, acc, 0, 0, 0);
    }
#pragma unroll
    for (int r2 = 0; r2 < 4; ++r2) {
      int gr = nb + quad * 4 + r2;
      outH[(size_t)gr * 128 + nt * 16 + colb] = (u16)bf16_rtne(acc[r2]);
    }
  }
}

// ---------------- Aggregation (layer 2): one wave per node -> f32 out ----------------

__global__ __launch_bounds__(256) void k_agg(const uint* __restrict__ hb, const float* __restrict__ dinv,
                                             const int* __restrict__ rowptr, const int* __restrict__ ep,
                                             const float* __restrict__ bias,
                                             float* __restrict__ outf) {
  int wid = threadIdx.x >> 6;
  int lane = threadIdx.x & 63;
  int node = blockIdx.x * 4 + wid;
  if (node >= N_NODES) return;
  int beg = rowptr[node];
  int end = rowptr[node + 1];
  float dn = dinv[node];
  float ax = 0.f, ay = 0.f;
  agg_node(hb, dinv, ep, node, lane, beg, end, dn, ax, ay);
  int c = lane * 2;
  float2 o;
  o.x = dn * ax + bias[c];
  o.y = dn * ay + bias[c + 1];
  *(float2*)(outf + (size_t)node * 128 + c) = o;
}

// ---------------- launch ----------------

extern "C" void kernel_launch(void* const* d_in, const int* in_sizes, int n_in,
                              void* d_out, int out_size, void* d_ws, size_t ws_size,
                              hipStream_t stream) {
  const float* x  = (const float*)d_in[0];
  const int*   ei = (const int*)d_in[1];   // int32: [0..E)=src, [E..2E)=dst
  const float* W1 = (const float*)d_in[2];
  const float* b1 = (const float*)d_in[3];
  const float* W2 = (const float*)d_in[4];
  const float* b2 = (const float*)d_in[5];
  float* out = (float*)d_out;

  char* p = (char*)d_ws;
  uint*  hb     = (uint*)p;  p += (size_t)N_NODES * 64 * sizeof(uint);            // 25.6 MB layer-1 h table
  int*   ep     = (int*)p;   p += (size_t)N_EDGES * sizeof(int);                  // 6.4 MB (src only)
  uint*  wsw1   = (uint*)p;  p += 8192 * sizeof(uint);                            // 32 KB
  uint*  wsw2   = (uint*)p;  p += 8192 * sizeof(uint);                            // 32 KB
  float* dinv   = (float*)p; p += (size_t)N_NODES * sizeof(float);                // 400 KB
  int*   rowptr = (int*)p;   p += (size_t)(N_NODES + 1) * sizeof(int);            // 400 KB
  int*   bin_cur= (int*)p;   p += (size_t)NBIN * sizeof(int);
  int*   ebase  = (int*)p;   p += (size_t)NBIN * sizeof(int);
  p = (char*)(((uintptr_t)p + 63) & ~(uintptr_t)63);
  // stage (7.2 MB) is dead after k_bin2; layer-2 h table (25.6 MB) aliases it.
  uint*  stage  = (uint*)p;
  uint*  hb2    = (uint*)p;   // total ws footprint ~58.6 MB

  const int GG = (N_NODES + 63) / 64;  // 1563

  k_zerobc<<<1, 256, 0, stream>>>(bin_cur);
  k_part<<<PBLK, 256, 0, stream>>>(ei, bin_cur, stage);
  k_binscan<<<1, 256, 0, stream>>>(bin_cur, ebase, rowptr);
  k_bin2<<<NBIN, 256, 0, stream>>>(bin_cur, stage, ebase, dinv, rowptr, ep);
  k_prepw<<<dim3(8, 2), 256, 0, stream>>>(W1, W2, wsw1, wsw2);

  // layer 1 GEMM: hb = bf16(x @ W1)
  k_gemm<<<GG, 256, 0, stream>>>(x, 1, wsw1, (u16*)hb, N_NODES);
  // fused: h1 = agg(hb)+b1 ; hb2 = bf16(h1 @ W2)
  k_aggm<<<N_NODES / 16, 256, 0, stream>>>(hb, dinv, rowptr, ep, b1, wsw2, (u16*)hb2);
  // layer 2 aggregation -> f32 out
  k_agg<<<(N_NODES + 3) / 4, 256, 0, stream>>>(hb2, dinv, rowptr, ep, b2, out);
}